// Round 8
// baseline (84.954 us; speedup 1.0000x reference)
//
#include <hip/hip_runtime.h>
#include <hip/hip_bf16.h>

typedef unsigned short u16;
typedef __attribute__((ext_vector_type(8))) short short8;
typedef __attribute__((ext_vector_type(4))) float f32x4;

#define MFMA16(a,b,c) __builtin_amdgcn_mfma_f32_16x16x32_bf16(a,b,c,0,0,0)

__device__ __forceinline__ u16 f2bf(float x){
  union { float f; unsigned u; } v; v.f = x;
  unsigned r = v.u + 0x7FFFu + ((v.u >> 16) & 1u);   // RTNE
  return (u16)(r >> 16);
}

__device__ __forceinline__ short8 pack8(float4 a, float4 b){
  short8 p;
  p[0]=(short)f2bf(a.x); p[1]=(short)f2bf(a.y); p[2]=(short)f2bf(a.z); p[3]=(short)f2bf(a.w);
  p[4]=(short)f2bf(b.x); p[5]=(short)f2bf(b.y); p[6]=(short)f2bf(b.z); p[7]=(short)f2bf(b.w);
  return p;
}

__device__ __forceinline__ void gload_lds16(const void* g, void* l){
  __builtin_amdgcn_global_load_lds(
      (const __attribute__((address_space(1))) unsigned int*)g,
      (__attribute__((address_space(3))) unsigned int*)l, 16, 0, 0);
}

// =============== kPrep: W1-permute + W2 transpose + GEMM3(f32,tiled) ======
__global__ __launch_bounds__(256) void kprep(
    const float* __restrict__ W1, const float* __restrict__ W2,
    const float* __restrict__ feat, const float* __restrict__ W3,
    u16* __restrict__ w1bp, float* __restrict__ W2T, float* __restrict__ l3p)
{
  __shared__ float tile[32][33];
  __shared__ __attribute__((aligned(16))) float At[32*68];
  __shared__ __attribute__((aligned(16))) float Bt[32*68];
  const int bid = blockIdx.x;
  const int t = threadIdx.x;

  if (bid < 320){
    int gid = bid * 256 + t;
    int kseg = gid / 1280;
    int rem = gid - kseg * 1280;
    int f = rem >> 6, l = rem & 63;
    int row = f * 16 + (l & 15);
    int col = kseg * 32 + (l >> 4) * 8;
    const float4* s = (const float4*)(W1 + (size_t)row * 2048 + col);
    float4 a = s[0], b = s[1];
    *(short8*)(w1bp + (size_t)gid * 8) = pack8(a, b);
  } else if (bid < 640){
    const int bb = bid - 320;
    const int tx = t & 31, ty = t >> 5;          // 32 x 8
    const int bx = bb & 31;                      // c tile (32 -> 1024)
    const int by = bb >> 5;                      // a tile (10 -> 320)
#pragma unroll
    for (int k = 0; k < 4; ++k){
      int c = bx*32 + ty + k*8;
      int a = by*32 + tx;
      tile[ty + k*8][tx] = (c < 1000) ? W2[(size_t)c*320 + a] : 0.f;
    }
    __syncthreads();
#pragma unroll
    for (int k = 0; k < 4; ++k){
      int a = by*32 + ty + k*8;
      int c = bx*32 + tx;
      W2T[(size_t)a*1024 + c] = tile[tx][ty + k*8];
    }
  } else {
    // ---- GEMM3: 64x64 C tile, K chunk 128 (4 stages of 32) ----
    const int bb = bid - 640;
    const int kg = bb & 15;              // K chunk of 128
    const int cg = bb >> 4;              // 16 c-groups of 64
    const int cbase = cg * 64;
    const int tm = t >> 4, tn = t & 15;  // 16x16 threads, 4x4 microtile
    const int sr = t >> 2, skc = (t & 3) * 8;  // staging: row, k-chunk
    f32x4 acc4[4];
#pragma unroll
    for (int i = 0; i < 4; ++i) acc4[i] = (f32x4){0.f,0.f,0.f,0.f};

    for (int st = 0; st < 4; ++st){
      const int kbase = kg*128 + st*32;
      {
        const float4* s = (const float4*)(feat + (size_t)sr*2048 + kbase + skc);
        float4 v0 = s[0], v1 = s[1];
        At[(skc+0)*68 + sr] = v0.x; At[(skc+1)*68 + sr] = v0.y;
        At[(skc+2)*68 + sr] = v0.z; At[(skc+3)*68 + sr] = v0.w;
        At[(skc+4)*68 + sr] = v1.x; At[(skc+5)*68 + sr] = v1.y;
        At[(skc+6)*68 + sr] = v1.z; At[(skc+7)*68 + sr] = v1.w;
      }
      {
        int c = cbase + sr;
        float4 v0 = {0,0,0,0}, v1 = {0,0,0,0};
        if (c < 1000){
          const float4* s = (const float4*)(W3 + (size_t)c*2048 + kbase + skc);
          v0 = s[0]; v1 = s[1];
        }
        Bt[(skc+0)*68 + sr] = v0.x; Bt[(skc+1)*68 + sr] = v0.y;
        Bt[(skc+2)*68 + sr] = v0.z; Bt[(skc+3)*68 + sr] = v0.w;
        Bt[(skc+4)*68 + sr] = v1.x; Bt[(skc+5)*68 + sr] = v1.y;
        Bt[(skc+6)*68 + sr] = v1.z; Bt[(skc+7)*68 + sr] = v1.w;
      }
      __syncthreads();
#pragma unroll
      for (int kk = 0; kk < 32; ++kk){
        f32x4 a = *(const f32x4*)(At + kk*68 + tm*4);
        f32x4 b = *(const f32x4*)(Bt + kk*68 + tn*4);
        acc4[0] += a[0] * b;
        acc4[1] += a[1] * b;
        acc4[2] += a[2] * b;
        acc4[3] += a[3] * b;
      }
      __syncthreads();
    }
#pragma unroll
    for (int i = 0; i < 4; ++i)
      *(f32x4*)(l3p + (size_t)kg*65536 + (tm*4+i)*1024 + cbase + tn*4) = acc4[i];
  }
}

// =============== K1: GEMM1 + softmax + region partial sums ================
// grid 196 (M=64), block 512 (8 waves: wm 2 x wc 4). BK=64, 32 chunks.
// B: global_load_lds DMA -> dbuf LDS (40KB x2), frags via ds_read_b128.
// A: regs -> pack bf16 -> swizzled LDS dbuf (8KB x2).
// Per iter: [DMA B(k+1)] [A(k+2)->regs] [MFMA(k)] [ds_write A(k+1)]
//           [s_waitcnt vmcnt(2) lgkmcnt(0); s_barrier]  (A loads stay in flight)
__global__ __launch_bounds__(512, 1) void k1_main(
    const float* __restrict__ am, const u16* __restrict__ w1bp,
    float* __restrict__ partial)
{
  __shared__ __attribute__((aligned(16))) u16 Bl[2][20480];  // 2 x 40 KB
  __shared__ __attribute__((aligned(16))) u16 sA[2][4096];   // 2 x 8 KB swizzled
  __shared__ float redM[64][4];
  __shared__ float redS[64][4];

  const int t = threadIdx.x;
  const int wv = t >> 6, l = t & 63;
  const int wm = wv >> 2, wc = wv & 3;
  const int llo = l & 15, lhi = l >> 4;
  const int blk = blockIdx.x;
  const int phase = (blk * 5) & 31;

  f32x4 acc0[5], acc1[5];
#pragma unroll
  for (int f = 0; f < 5; ++f){ acc0[f] = (f32x4){0,0,0,0}; acc1[f] = (f32x4){0,0,0,0}; }

  // A staging: row ar (0..63), 8-f32 slot j (0..7) of each 64-k chunk
  const int ar = t >> 3, j = t & 7;
  const float* arow = am + (size_t)(blk*64 + ar)*2048 + j*8;
  const int aw = ar*128 + (j ^ (ar & 7))*16;              // byte offset in sA buf

  // B DMA: this thread copies 5 x 1KB chunks (cidx = p*8 + wv), lane gives 16B
  const char* const w1c = (const char*)w1bp;

  // MFMA read bases
  const int ab0 = (wm*32 + llo)*128, ab1 = ab0 + 16*128;
  const int sw = llo & 7;
  const int bq = (wc*5) << 10;   // byte offset of this wave's first frag

  float4 RE0, RE1, RO0, RO1;

  // ---------------- prologue ----------------
  {
    const int kp0 = phase, kp1 = (phase + 1) & 31;
#pragma unroll
    for (int p = 0; p < 5; ++p){
      int cidx = p*8 + wv;
      gload_lds16(w1c + (size_t)kp0*40960 + cidx*1024 + l*16,
                  (char*)&Bl[0][0] + cidx*1024);
    }
    const float4* a0p = (const float4*)(arow + kp0*64);
    const float4* a1p = (const float4*)(arow + kp1*64);
    RE0 = a0p[0]; RE1 = a0p[1];
    RO0 = a1p[0]; RO1 = a1p[1];
    *(short8*)((char*)&sA[0][0] + aw) = pack8(RE0, RE1);
    asm volatile("s_waitcnt vmcnt(0) lgkmcnt(0)\n\ts_barrier" ::: "memory");
  }

#define MFMA_STEP(CUR)                                                        \
  {                                                                           \
    const char* sac = (const char*)&sA[CUR][0];                               \
    const char* blc = (const char*)&Bl[CUR][0];                               \
    _Pragma("unroll")                                                         \
    for (int ks = 0; ks < 2; ++ks){                                           \
      int slot = ((ks*4 + lhi) ^ sw) * 16;                                    \
      short8 a0 = *(const short8*)(sac + ab0 + slot);                         \
      short8 a1 = *(const short8*)(sac + ab1 + slot);                         \
      _Pragma("unroll")                                                       \
      for (int f = 0; f < 5; ++f){                                            \
        short8 bf = *(const short8*)(blc + bq + ((ks*20 + f) << 10) + l*16);  \
        acc0[f] = MFMA16(a0, bf, acc0[f]);                                    \
        acc1[f] = MFMA16(a1, bf, acc1[f]);                                    \
      }                                                                       \
    }                                                                         \
  }

#define DMA_CHUNK(KP, BUF)                                                    \
  {                                                                           \
    _Pragma("unroll")                                                         \
    for (int p = 0; p < 5; ++p){                                              \
      int cidx = p*8 + wv;                                                    \
      gload_lds16(w1c + (size_t)(KP)*40960 + cidx*1024 + l*16,                \
                  (char*)&Bl[BUF][0] + cidx*1024);                            \
    }                                                                         \
  }

#define WAIT2BAR() asm volatile("s_waitcnt vmcnt(2) lgkmcnt(0)\n\ts_barrier" ::: "memory")

  // ---------------- steady loop: k = 0..29 (15 pairs) ----------------
#pragma unroll 1
  for (int k2 = 0; k2 < 15; ++k2){
    // even k = 2*k2 : compute buf0, DMA->buf1, A(k+2)->RE, DSW(RO)->sA1
    {
      const int kpB = (phase + 2*k2 + 1) & 31;
      const int kpA = (phase + 2*k2 + 2) & 31;
      DMA_CHUNK(kpB, 1);
      const float4* ap = (const float4*)(arow + kpA*64);
      RE0 = ap[0]; RE1 = ap[1];
      MFMA_STEP(0);
      *(short8*)((char*)&sA[1][0] + aw) = pack8(RO0, RO1);
      WAIT2BAR();
    }
    // odd k = 2*k2+1 : compute buf1, DMA->buf0, A(k+2)->RO, DSW(RE)->sA0
    {
      const int kpB = (phase + 2*k2 + 2) & 31;
      const int kpA = (phase + 2*k2 + 3) & 31;
      DMA_CHUNK(kpB, 0);
      const float4* ap = (const float4*)(arow + kpA*64);
      RO0 = ap[0]; RO1 = ap[1];
      MFMA_STEP(1);
      *(short8*)((char*)&sA[0][0] + aw) = pack8(RE0, RE1);
      WAIT2BAR();
    }
  }
  // ---------------- tail: k = 30, 31 ----------------
  {
    const int kpB = (phase + 31) & 31;
    DMA_CHUNK(kpB, 1);
    MFMA_STEP(0);
    *(short8*)((char*)&sA[1][0] + aw) = pack8(RO0, RO1);
    asm volatile("s_waitcnt vmcnt(0) lgkmcnt(0)\n\ts_barrier" ::: "memory");
  }
  MFMA_STEP(1);

  // ---- epilogue: softmax over 320 cols; rows = wm*32 + m16*16 + lhi*4 + r
  float rmax0[4], rmax1[4];
#pragma unroll
  for (int r = 0; r < 4; ++r){
    float x0 = acc0[0][r], x1 = acc1[0][r];
#pragma unroll
    for (int f = 1; f < 5; ++f){ x0 = fmaxf(x0, acc0[f][r]); x1 = fmaxf(x1, acc1[f][r]); }
#pragma unroll
    for (int off = 1; off < 16; off <<= 1){
      x0 = fmaxf(x0, __shfl_xor(x0, off));
      x1 = fmaxf(x1, __shfl_xor(x1, off));
    }
    rmax0[r] = x0; rmax1[r] = x1;
  }
  if (llo == 0){
#pragma unroll
    for (int r = 0; r < 4; ++r){
      redM[wm*32 +      lhi*4 + r][wc] = rmax0[r];
      redM[wm*32 + 16 + lhi*4 + r][wc] = rmax1[r];
    }
  }
  __syncthreads();
#pragma unroll
  for (int r = 0; r < 4; ++r){
    int r0 = wm*32 + lhi*4 + r, r1 = r0 + 16;
    rmax0[r] = fmaxf(fmaxf(redM[r0][0], redM[r0][1]), fmaxf(redM[r0][2], redM[r0][3]));
    rmax1[r] = fmaxf(fmaxf(redM[r1][0], redM[r1][1]), fmaxf(redM[r1][2], redM[r1][3]));
  }
  float rsum0[4], rsum1[4];
#pragma unroll
  for (int r = 0; r < 4; ++r){
    float s0 = 0.f, s1 = 0.f;
#pragma unroll
    for (int f = 0; f < 5; ++f){
      float e0 = __expf(acc0[f][r] - rmax0[r]);
      float e1 = __expf(acc1[f][r] - rmax1[r]);
      acc0[f][r] = e0; acc1[f][r] = e1;
      s0 += e0; s1 += e1;
    }
#pragma unroll
    for (int off = 1; off < 16; off <<= 1){
      s0 += __shfl_xor(s0, off);
      s1 += __shfl_xor(s1, off);
    }
    rsum0[r] = s0; rsum1[r] = s1;
  }
  if (llo == 0){
#pragma unroll
    for (int r = 0; r < 4; ++r){
      redS[wm*32 +      lhi*4 + r][wc] = rsum0[r];
      redS[wm*32 + 16 + lhi*4 + r][wc] = rsum1[r];
    }
  }
  __syncthreads();
#pragma unroll
  for (int r = 0; r < 4; ++r){
    int r0 = wm*32 + lhi*4 + r, r1 = r0 + 16;
    rmax0[r] = 1.f / (redS[r0][0] + redS[r0][1] + redS[r0][2] + redS[r0][3]);
    rmax1[r] = 1.f / (redS[r1][0] + redS[r1][1] + redS[r1][2] + redS[r1][3]);
  }
  const int n0h = blk*64 + wm*32;
  const int thr = 196 * (n0h/196 + 1) - n0h;     // rows-in-half < thr -> seg0
  float sseg0[5] = {0,0,0,0,0}, sseg1[5] = {0,0,0,0,0};
#pragma unroll
  for (int r = 0; r < 4; ++r){
    int rh0 = lhi*4 + r, rh1 = rh0 + 16;
    bool in00 = rh0 < thr, in01 = rh1 < thr;
#pragma unroll
    for (int f = 0; f < 5; ++f){
      float v0 = acc0[f][r] * rmax0[r];
      float v1 = acc1[f][r] * rmax1[r];
      sseg0[f] += (in00 ? v0 : 0.f) + (in01 ? v1 : 0.f);
      sseg1[f] += (in00 ? 0.f : v0) + (in01 ? 0.f : v1);
    }
  }
#pragma unroll
  for (int f = 0; f < 5; ++f){
    sseg0[f] += __shfl_xor(sseg0[f], 16); sseg0[f] += __shfl_xor(sseg0[f], 32);
    sseg1[f] += __shfl_xor(sseg1[f], 16); sseg1[f] += __shfl_xor(sseg1[f], 32);
  }
  if (lhi == 0){
    const int vblk = blk*2 + wm;
#pragma unroll
    for (int f = 0; f < 5; ++f){
      partial[vblk*640 +       wc*80 + f*16 + llo] = sseg0[f];
      partial[vblk*640 + 320 + wc*80 + f*16 + llo] = sseg1[f];
    }
  }
}

// =============== K2c: reduce partials + attr_dis@W2T + both softmax =======
__global__ __launch_bounds__(256) void k2c_final(
    const float* __restrict__ partialp, const float* __restrict__ W2T,
    const float* __restrict__ l3p, float* __restrict__ outp,
    float* __restrict__ out_ad)
{
  __shared__ __attribute__((aligned(16))) float sad[320];
  __shared__ float redA[4], redB[4];
  const int b = blockIdx.x, t = threadIdx.x;
  const int w = t >> 6, l = t & 63;
  const int lo = (196*b) >> 5, hi = (196*b + 195) >> 5;
  for (int i = t; i < 320; i += 256){
    float s = 0.f;
    for (int blk = lo; blk <= hi; ++blk){
      int seg = b - (blk*32)/196;
      if (seg >= 0 && seg < 2) s += partialp[blk*640 + seg*320 + i];
    }
    s *= (1.f / 320.f);
    sad[i] = s;
    out_ad[b*320 + i] = s;
  }
  __syncthreads();
  const int c0 = t * 4;
  f32x4 s2v = {0.f,0.f,0.f,0.f};
  const float4* a4 = (const float4*)sad;
#pragma unroll 4
  for (int i = 0; i < 80; ++i){
    float4 sv = a4[i];
    f32x4 w0 = *(const f32x4*)(W2T + (size_t)(4*i  )*1024 + c0);
    f32x4 w1 = *(const f32x4*)(W2T + (size_t)(4*i+1)*1024 + c0);
    f32x4 w2 = *(const f32x4*)(W2T + (size_t)(4*i+2)*1024 + c0);
    f32x4 w3 = *(const f32x4*)(W2T + (size_t)(4*i+3)*1024 + c0);
    s2v += sv.x*w0 + sv.y*w1 + sv.z*w2 + sv.w*w3;
  }
  f32x4 s3v = {0.f,0.f,0.f,0.f};
#pragma unroll
  for (int kg = 0; kg < 16; ++kg)
    s3v += *(const f32x4*)(l3p + (size_t)kg*65536 + b*1024 + c0);
  float l2a[4], l3a[4];
#pragma unroll
  for (int jj = 0; jj < 4; ++jj){
    bool valid = (c0 + jj) < 1000;
    l2a[jj] = valid ? s2v[jj] : -3.4e38f;
    l3a[jj] = valid ? s3v[jj] : -3.4e38f;
  }
  float m2 = fmaxf(fmaxf(l2a[0],l2a[1]), fmaxf(l2a[2],l2a[3]));
  float m3 = fmaxf(fmaxf(l3a[0],l3a[1]), fmaxf(l3a[2],l3a[3]));
#pragma unroll
  for (int off = 32; off > 0; off >>= 1){
    m2 = fmaxf(m2, __shfl_xor(m2, off));
    m3 = fmaxf(m3, __shfl_xor(m3, off));
  }
  if (l == 0){ redA[w] = m2; redB[w] = m3; }
  __syncthreads();
  m2 = fmaxf(fmaxf(redA[0],redA[1]), fmaxf(redA[2],redA[3]));
  m3 = fmaxf(fmaxf(redB[0],redB[1]), fmaxf(redB[2],redB[3]));
  __syncthreads();
  float e2[4], e3[4], s2 = 0.f, s3 = 0.f;
#pragma unroll
  for (int jj = 0; jj < 4; ++jj){
    bool valid = (c0 + jj) < 1000;
    e2[jj] = valid ? __expf(l2a[jj] - m2) : 0.f;
    e3[jj] = valid ? __expf(l3a[jj] - m3) : 0.f;
    s2 += e2[jj]; s3 += e3[jj];
  }
#pragma unroll
  for (int off = 32; off > 0; off >>= 1){
    s2 += __shfl_xor(s2, off);
    s3 += __shfl_xor(s3, off);
  }
  if (l == 0){ redA[w] = s2; redB[w] = s3; }
  __syncthreads();
  s2 = redA[0] + redA[1] + redA[2] + redA[3];
  s3 = redB[0] + redB[1] + redB[2] + redB[3];
  float i2 = 1.f / s2, i3 = 1.f / s3;
#pragma unroll
  for (int jj = 0; jj < 4; ++jj){
    int c = c0 + jj;
    if (c < 1000) outp[b*1000 + c] = 0.5f * (e2[jj]*i2 + e3[jj]*i3);
  }
}

extern "C" void kernel_launch(void* const* d_in, const int* in_sizes, int n_in,
                              void* d_out, int out_size, void* d_ws, size_t ws_size,
                              hipStream_t stream)
{
  const float* attr_map = (const float*)d_in[0];
  const float* features = (const float*)d_in[1];
  const float* W1 = (const float*)d_in[2];
  const float* W2 = (const float*)d_in[3];
  const float* W3 = (const float*)d_in[4];
  float* outp = (float*)d_out;

  char* ws = (char*)d_ws;
  u16*   w1bp    = (u16*)ws;                       // 1,310,720 B
  float* W2T     = (float*)(ws + 1310720);         // 1,310,720 B
  float* partial = (float*)(ws + 2621440);         // 1,003,520 B
  float* l3p     = (float*)(ws + 3624960);         // 4,194,304 B (total 7.8 MB)

  kprep    <<<896, 256, 0, stream>>>(W1, W2, features, W3, w1bp, W2T, l3p);
  k1_main  <<<196, 512, 0, stream>>>(attr_map, w1bp, partial);
  k2c_final<<<64, 256, 0, stream>>>(partial, W2T, l3p, outp, outp + 64000);
}

// Round 9
// 77.813 us; speedup vs baseline: 1.0918x; 1.0918x over previous
//
#include <hip/hip_runtime.h>
#include <hip/hip_bf16.h>

typedef unsigned short u16;
typedef __attribute__((ext_vector_type(8))) short short8;
typedef __attribute__((ext_vector_type(4))) float f32x4;

#define MFMA16(a,b,c) __builtin_amdgcn_mfma_f32_16x16x32_bf16(a,b,c,0,0,0)

__device__ __forceinline__ u16 f2bf(float x){
  union { float f; unsigned u; } v; v.f = x;
  unsigned r = v.u + 0x7FFFu + ((v.u >> 16) & 1u);   // RTNE
  return (u16)(r >> 16);
}

__device__ __forceinline__ short8 pack8(float4 a, float4 b){
  short8 p;
  p[0]=(short)f2bf(a.x); p[1]=(short)f2bf(a.y); p[2]=(short)f2bf(a.z); p[3]=(short)f2bf(a.w);
  p[4]=(short)f2bf(b.x); p[5]=(short)f2bf(b.y); p[6]=(short)f2bf(b.z); p[7]=(short)f2bf(b.w);
  return p;
}

__device__ __forceinline__ void gload_lds16(const void* g, void* l){
  __builtin_amdgcn_global_load_lds(
      (const __attribute__((address_space(1))) unsigned int*)g,
      (__attribute__((address_space(3))) unsigned int*)l, 16, 0, 0);
}

// =============== kPrep: W1-permute + W2 transpose + GEMM3(f32,tiled) ======
__global__ __launch_bounds__(256) void kprep(
    const float* __restrict__ W1, const float* __restrict__ W2,
    const float* __restrict__ feat, const float* __restrict__ W3,
    u16* __restrict__ w1bp, float* __restrict__ W2T, float* __restrict__ l3p)
{
  __shared__ float tile[32][33];
  __shared__ __attribute__((aligned(16))) float At[32*68];
  __shared__ __attribute__((aligned(16))) float Bt[32*68];
  const int bid = blockIdx.x;
  const int t = threadIdx.x;

  if (bid < 320){
    int gid = bid * 256 + t;
    int kseg = gid / 1280;
    int rem = gid - kseg * 1280;
    int f = rem >> 6, l = rem & 63;
    int row = f * 16 + (l & 15);
    int col = kseg * 32 + (l >> 4) * 8;
    const float4* s = (const float4*)(W1 + (size_t)row * 2048 + col);
    float4 a = s[0], b = s[1];
    *(short8*)(w1bp + (size_t)gid * 8) = pack8(a, b);
  } else if (bid < 640){
    const int bb = bid - 320;
    const int tx = t & 31, ty = t >> 5;          // 32 x 8
    const int bx = bb & 31;                      // c tile (32 -> 1024)
    const int by = bb >> 5;                      // a tile (10 -> 320)
#pragma unroll
    for (int k = 0; k < 4; ++k){
      int c = bx*32 + ty + k*8;
      int a = by*32 + tx;
      tile[ty + k*8][tx] = (c < 1000) ? W2[(size_t)c*320 + a] : 0.f;
    }
    __syncthreads();
#pragma unroll
    for (int k = 0; k < 4; ++k){
      int a = by*32 + ty + k*8;
      int c = bx*32 + tx;
      W2T[(size_t)a*1024 + c] = tile[tx][ty + k*8];
    }
  } else {
    // ---- GEMM3: 64x64 C tile, K chunk 128 (4 stages of 32) ----
    const int bb = bid - 640;
    const int kg = bb & 15;              // K chunk of 128
    const int cg = bb >> 4;              // 16 c-groups of 64
    const int cbase = cg * 64;
    const int tm = t >> 4, tn = t & 15;  // 16x16 threads, 4x4 microtile
    const int sr = t >> 2, skc = (t & 3) * 8;  // staging: row, k-chunk
    f32x4 acc4[4];
#pragma unroll
    for (int i = 0; i < 4; ++i) acc4[i] = (f32x4){0.f,0.f,0.f,0.f};

    for (int st = 0; st < 4; ++st){
      const int kbase = kg*128 + st*32;
      {
        const float4* s = (const float4*)(feat + (size_t)sr*2048 + kbase + skc);
        float4 v0 = s[0], v1 = s[1];
        At[(skc+0)*68 + sr] = v0.x; At[(skc+1)*68 + sr] = v0.y;
        At[(skc+2)*68 + sr] = v0.z; At[(skc+3)*68 + sr] = v0.w;
        At[(skc+4)*68 + sr] = v1.x; At[(skc+5)*68 + sr] = v1.y;
        At[(skc+6)*68 + sr] = v1.z; At[(skc+7)*68 + sr] = v1.w;
      }
      {
        int c = cbase + sr;
        float4 v0 = {0,0,0,0}, v1 = {0,0,0,0};
        if (c < 1000){
          const float4* s = (const float4*)(W3 + (size_t)c*2048 + kbase + skc);
          v0 = s[0]; v1 = s[1];
        }
        Bt[(skc+0)*68 + sr] = v0.x; Bt[(skc+1)*68 + sr] = v0.y;
        Bt[(skc+2)*68 + sr] = v0.z; Bt[(skc+3)*68 + sr] = v0.w;
        Bt[(skc+4)*68 + sr] = v1.x; Bt[(skc+5)*68 + sr] = v1.y;
        Bt[(skc+6)*68 + sr] = v1.z; Bt[(skc+7)*68 + sr] = v1.w;
      }
      __syncthreads();
#pragma unroll
      for (int kk = 0; kk < 32; ++kk){
        f32x4 a = *(const f32x4*)(At + kk*68 + tm*4);
        f32x4 b = *(const f32x4*)(Bt + kk*68 + tn*4);
        acc4[0] += a[0] * b;
        acc4[1] += a[1] * b;
        acc4[2] += a[2] * b;
        acc4[3] += a[3] * b;
      }
      __syncthreads();
    }
#pragma unroll
    for (int i = 0; i < 4; ++i)
      *(f32x4*)(l3p + (size_t)kg*65536 + (tm*4+i)*1024 + cbase + tn*4) = acc4[i];
  }
}

// =============== K1: GEMM1 + softmax + region partial sums ================
// grid 196 (M=64), block 512 (8 waves: wm 2 x wc 4). BK=64, 32 chunks.
// Depth-pipelined: 3 B LDS bufs (DMA depth 2), 3 A reg sets (depth 3),
// 2 A LDS bufs. Per iter: [dsw A(k+1)] [DMA B(k+2)] [issue A(k+3)] [MFMA(k)]
// [vmcnt(9) lgkm(0) barrier] -- retires DMA(k+1), keeps A(k+2),A(k+3),DMA(k+2).
__global__ __launch_bounds__(512, 1) void k1_main(
    const float* __restrict__ am, const u16* __restrict__ w1bp,
    float* __restrict__ partial)
{
  __shared__ __attribute__((aligned(16))) u16 Bl[3][20480];  // 3 x 40 KB
  __shared__ __attribute__((aligned(16))) u16 sA[2][4096];   // 2 x 8 KB swizzled
  __shared__ float redM[64][4];
  __shared__ float redS[64][4];

  const int t = threadIdx.x;
  const int wv = t >> 6, l = t & 63;
  const int wm = wv >> 2, wc = wv & 3;
  const int llo = l & 15, lhi = l >> 4;
  const int blk = blockIdx.x;
  const int phase = (blk * 5) & 31;

  f32x4 acc0[5], acc1[5];
#pragma unroll
  for (int f = 0; f < 5; ++f){ acc0[f] = (f32x4){0,0,0,0}; acc1[f] = (f32x4){0,0,0,0}; }

  // A staging: row ar (0..63), 8-f32 slot j (0..7) of each 64-k chunk
  const int ar = t >> 3, j = t & 7;
  const float* arow = am + (size_t)(blk*64 + ar)*2048 + j*8;
  const int aw = ar*128 + (j ^ (ar & 7))*16;              // byte offset in sA buf

  const char* const w1c = (const char*)w1bp;

  // MFMA read bases
  const int ab0 = (wm*32 + llo)*128, ab1 = ab0 + 16*128;
  const int sw = llo & 7;
  const int bq = (wc*5) << 10;   // byte offset of this wave's first frag

  float4 A0a, A0b, A1a, A1b, A2a, A2b;   // 3 A register sets

#define DMA_CHUNK(KP, BUF)                                                    \
  {                                                                           \
    _Pragma("unroll")                                                         \
    for (int p = 0; p < 5; ++p){                                              \
      int cidx = p*8 + wv;                                                    \
      gload_lds16(w1c + (size_t)(KP)*40960 + cidx*1024 + l*16,                \
                  (char*)&Bl[BUF][0] + cidx*1024);                            \
    }                                                                         \
  }

#define MFMA_STEP(AB, BB)                                                     \
  {                                                                           \
    const char* sac = (const char*)&sA[AB][0];                                \
    const char* blc = (const char*)&Bl[BB][0];                                \
    _Pragma("unroll")                                                         \
    for (int ks = 0; ks < 2; ++ks){                                           \
      int slot = ((ks*4 + lhi) ^ sw) * 16;                                    \
      short8 a0 = *(const short8*)(sac + ab0 + slot);                         \
      short8 a1 = *(const short8*)(sac + ab1 + slot);                         \
      _Pragma("unroll")                                                       \
      for (int f = 0; f < 5; ++f){                                            \
        short8 bf = *(const short8*)(blc + bq + ((ks*20 + f) << 10) + l*16);  \
        acc0[f] = MFMA16(a0, bf, acc0[f]);                                    \
        acc1[f] = MFMA16(a1, bf, acc1[f]);                                    \
      }                                                                       \
    }                                                                         \
  }

  // STEP(k): dsw A(k+1)[set (k+1)%3 -> sA[(k+1)%2]]; DMA B(k+2)->Bl[(k+2)%3];
  //          load A(k+3)->set k%3; MFMA(k) from sA[k%2], Bl[k%3]; wait+bar.
#define STEP(KK, WA, WB, LA, LB, ABN, BB, BBN, DOA, DODMA, VMN)               \
  {                                                                           \
    *(short8*)((char*)&sA[ABN][0] + aw) = pack8(WA, WB);                      \
    if (DODMA){ int kp = (phase + (KK) + 2) & 31; DMA_CHUNK(kp, BBN); }       \
    if (DOA){ int kp = (phase + (KK) + 3) & 31;                               \
      const float4* ap = (const float4*)(arow + kp*64);                       \
      LA = ap[0]; LB = ap[1]; }                                               \
    MFMA_STEP(1-(ABN), BB);                                                   \
    asm volatile("s_waitcnt vmcnt(" #VMN ") lgkmcnt(0)\n\ts_barrier" ::: "memory"); \
  }

  // ---------------- prologue ----------------
  {
    DMA_CHUNK(phase, 0);                                   // DMA(0)
    const float4* a0p = (const float4*)(arow + phase*64);  // A(0) -> set0
    A0a = a0p[0]; A0b = a0p[1];
    const float4* a1p = (const float4*)(arow + (((phase+1)&31)*64));
    A1a = a1p[0]; A1b = a1p[1];                            // A(1) -> set1
    *(short8*)((char*)&sA[0][0] + aw) = pack8(A0a, A0b);   // waits A(0) (+DMA0)
    DMA_CHUNK((phase+1)&31, 1);                            // DMA(1)
    const float4* a2p = (const float4*)(arow + (((phase+2)&31)*64));
    A2a = a2p[0]; A2b = a2p[1];                            // A(2) -> set2
    asm volatile("s_waitcnt lgkmcnt(0)\n\ts_barrier" ::: "memory");
  }

  // ---------------- steady: k = 0..23 (4 x unroll-6) ----------------
  int kb = 0;
#pragma unroll 1
  for (int k6 = 0; k6 < 4; ++k6){
    STEP(kb+0, A1a,A1b, A0a,A0b, 1, 0, 2, 1, 1, 9);
    STEP(kb+1, A2a,A2b, A1a,A1b, 0, 1, 0, 1, 1, 9);
    STEP(kb+2, A0a,A0b, A2a,A2b, 1, 2, 1, 1, 1, 9);
    STEP(kb+3, A1a,A1b, A0a,A0b, 0, 0, 2, 1, 1, 9);
    STEP(kb+4, A2a,A2b, A1a,A1b, 1, 1, 0, 1, 1, 9);
    STEP(kb+5, A0a,A0b, A2a,A2b, 0, 2, 1, 1, 1, 9);
    kb += 6;
  }
  // ---------------- k = 24..29 ----------------
  STEP(24, A1a,A1b, A0a,A0b, 1, 0, 2, 1, 1, 9);
  STEP(25, A2a,A2b, A1a,A1b, 0, 1, 0, 1, 1, 9);
  STEP(26, A0a,A0b, A2a,A2b, 1, 2, 1, 1, 1, 9);
  STEP(27, A1a,A1b, A0a,A0b, 0, 0, 2, 1, 1, 9);
  STEP(28, A2a,A2b, A1a,A1b, 1, 1, 0, 1, 1, 9);
  STEP(29, A0a,A0b, A2a,A2b, 0, 2, 1, 0, 1, 7);   // no A issue
  // ---------------- k = 30 ----------------
  {
    *(short8*)((char*)&sA[1][0] + aw) = pack8(A1a, A1b);   // A(31), set1
    MFMA_STEP(0, 0);
    asm volatile("s_waitcnt vmcnt(0) lgkmcnt(0)\n\ts_barrier" ::: "memory");
  }
  // ---------------- k = 31 ----------------
  MFMA_STEP(1, 1);

#undef STEP
#undef MFMA_STEP
#undef DMA_CHUNK

  // ---- epilogue: softmax over 320 cols; rows = wm*32 + m16*16 + lhi*4 + r
  float rmax0[4], rmax1[4];
#pragma unroll
  for (int r = 0; r < 4; ++r){
    float x0 = acc0[0][r], x1 = acc1[0][r];
#pragma unroll
    for (int f = 1; f < 5; ++f){ x0 = fmaxf(x0, acc0[f][r]); x1 = fmaxf(x1, acc1[f][r]); }
#pragma unroll
    for (int off = 1; off < 16; off <<= 1){
      x0 = fmaxf(x0, __shfl_xor(x0, off));
      x1 = fmaxf(x1, __shfl_xor(x1, off));
    }
    rmax0[r] = x0; rmax1[r] = x1;
  }
  if (llo == 0){
#pragma unroll
    for (int r = 0; r < 4; ++r){
      redM[wm*32 +      lhi*4 + r][wc] = rmax0[r];
      redM[wm*32 + 16 + lhi*4 + r][wc] = rmax1[r];
    }
  }
  __syncthreads();
#pragma unroll
  for (int r = 0; r < 4; ++r){
    int r0 = wm*32 + lhi*4 + r, r1 = r0 + 16;
    rmax0[r] = fmaxf(fmaxf(redM[r0][0], redM[r0][1]), fmaxf(redM[r0][2], redM[r0][3]));
    rmax1[r] = fmaxf(fmaxf(redM[r1][0], redM[r1][1]), fmaxf(redM[r1][2], redM[r1][3]));
  }
  float rsum0[4], rsum1[4];
#pragma unroll
  for (int r = 0; r < 4; ++r){
    float s0 = 0.f, s1 = 0.f;
#pragma unroll
    for (int f = 0; f < 5; ++f){
      float e0 = __expf(acc0[f][r] - rmax0[r]);
      float e1 = __expf(acc1[f][r] - rmax1[r]);
      acc0[f][r] = e0; acc1[f][r] = e1;
      s0 += e0; s1 += e1;
    }
#pragma unroll
    for (int off = 1; off < 16; off <<= 1){
      s0 += __shfl_xor(s0, off);
      s1 += __shfl_xor(s1, off);
    }
    rsum0[r] = s0; rsum1[r] = s1;
  }
  if (llo == 0){
#pragma unroll
    for (int r = 0; r < 4; ++r){
      redS[wm*32 +      lhi*4 + r][wc] = rsum0[r];
      redS[wm*32 + 16 + lhi*4 + r][wc] = rsum1[r];
    }
  }
  __syncthreads();
#pragma unroll
  for (int r = 0; r < 4; ++r){
    int r0 = wm*32 + lhi*4 + r, r1 = r0 + 16;
    rmax0[r] = 1.f / (redS[r0][0] + redS[r0][1] + redS[r0][2] + redS[r0][3]);
    rmax1[r] = 1.f / (redS[r1][0] + redS[r1][1] + redS[r1][2] + redS[r1][3]);
  }
  const int n0h = blk*64 + wm*32;
  const int thr = 196 * (n0h/196 + 1) - n0h;     // rows-in-half < thr -> seg0
  float sseg0[5] = {0,0,0,0,0}, sseg1[5] = {0,0,0,0,0};
#pragma unroll
  for (int r = 0; r < 4; ++r){
    int rh0 = lhi*4 + r, rh1 = rh0 + 16;
    bool in00 = rh0 < thr, in01 = rh1 < thr;
#pragma unroll
    for (int f = 0; f < 5; ++f){
      float v0 = acc0[f][r] * rmax0[r];
      float v1 = acc1[f][r] * rmax1[r];
      sseg0[f] += (in00 ? v0 : 0.f) + (in01 ? v1 : 0.f);
      sseg1[f] += (in00 ? 0.f : v0) + (in01 ? 0.f : v1);
    }
  }
#pragma unroll
  for (int f = 0; f < 5; ++f){
    sseg0[f] += __shfl_xor(sseg0[f], 16); sseg0[f] += __shfl_xor(sseg0[f], 32);
    sseg1[f] += __shfl_xor(sseg1[f], 16); sseg1[f] += __shfl_xor(sseg1[f], 32);
  }
  if (lhi == 0){
    const int vblk = blk*2 + wm;
#pragma unroll
    for (int f = 0; f < 5; ++f){
      partial[vblk*640 +       wc*80 + f*16 + llo] = sseg0[f];
      partial[vblk*640 + 320 + wc*80 + f*16 + llo] = sseg1[f];
    }
  }
}

// =============== K2c: reduce partials + attr_dis@W2T + both softmax =======
__global__ __launch_bounds__(256) void k2c_final(
    const float* __restrict__ partialp, const float* __restrict__ W2T,
    const float* __restrict__ l3p, float* __restrict__ outp,
    float* __restrict__ out_ad)
{
  __shared__ __attribute__((aligned(16))) float sad[320];
  __shared__ float redA[4], redB[4];
  const int b = blockIdx.x, t = threadIdx.x;
  const int w = t >> 6, l = t & 63;
  const int lo = (196*b) >> 5, hi = (196*b + 195) >> 5;
  for (int i = t; i < 320; i += 256){
    float s = 0.f;
    for (int blk = lo; blk <= hi; ++blk){
      int seg = b - (blk*32)/196;
      if (seg >= 0 && seg < 2) s += partialp[blk*640 + seg*320 + i];
    }
    s *= (1.f / 320.f);
    sad[i] = s;
    out_ad[b*320 + i] = s;
  }
  __syncthreads();
  const int c0 = t * 4;
  f32x4 s2v = {0.f,0.f,0.f,0.f};
  const float4* a4 = (const float4*)sad;
#pragma unroll 4
  for (int i = 0; i < 80; ++i){
    float4 sv = a4[i];
    f32x4 w0 = *(const f32x4*)(W2T + (size_t)(4*i  )*1024 + c0);
    f32x4 w1 = *(const f32x4*)(W2T + (size_t)(4*i+1)*1024 + c0);
    f32x4 w2 = *(const f32x4*)(W2T + (size_t)(4*i+2)*1024 + c0);
    f32x4 w3 = *(const f32x4*)(W2T + (size_t)(4*i+3)*1024 + c0);
    s2v += sv.x*w0 + sv.y*w1 + sv.z*w2 + sv.w*w3;
  }
  f32x4 s3v = {0.f,0.f,0.f,0.f};
#pragma unroll
  for (int kg = 0; kg < 16; ++kg)
    s3v += *(const f32x4*)(l3p + (size_t)kg*65536 + b*1024 + c0);
  float l2a[4], l3a[4];
#pragma unroll
  for (int jj = 0; jj < 4; ++jj){
    bool valid = (c0 + jj) < 1000;
    l2a[jj] = valid ? s2v[jj] : -3.4e38f;
    l3a[jj] = valid ? s3v[jj] : -3.4e38f;
  }
  float m2 = fmaxf(fmaxf(l2a[0],l2a[1]), fmaxf(l2a[2],l2a[3]));
  float m3 = fmaxf(fmaxf(l3a[0],l3a[1]), fmaxf(l3a[2],l3a[3]));
#pragma unroll
  for (int off = 32; off > 0; off >>= 1){
    m2 = fmaxf(m2, __shfl_xor(m2, off));
    m3 = fmaxf(m3, __shfl_xor(m3, off));
  }
  if (l == 0){ redA[w] = m2; redB[w] = m3; }
  __syncthreads();
  m2 = fmaxf(fmaxf(redA[0],redA[1]), fmaxf(redA[2],redA[3]));
  m3 = fmaxf(fmaxf(redB[0],redB[1]), fmaxf(redB[2],redB[3]));
  __syncthreads();
  float e2[4], e3[4], s2 = 0.f, s3 = 0.f;
#pragma unroll
  for (int jj = 0; jj < 4; ++jj){
    bool valid = (c0 + jj) < 1000;
    e2[jj] = valid ? __expf(l2a[jj] - m2) : 0.f;
    e3[jj] = valid ? __expf(l3a[jj] - m3) : 0.f;
    s2 += e2[jj]; s3 += e3[jj];
  }
#pragma unroll
  for (int off = 32; off > 0; off >>= 1){
    s2 += __shfl_xor(s2, off);
    s3 += __shfl_xor(s3, off);
  }
  if (l == 0){ redA[w] = s2; redB[w] = s3; }
  __syncthreads();
  s2 = redA[0] + redA[1] + redA[2] + redA[3];
  s3 = redB[0] + redB[1] + redB[2] + redB[3];
  float i2 = 1.f / s2, i3 = 1.f / s3;
#pragma unroll
  for (int jj = 0; jj < 4; ++jj){
    int c = c0 + jj;
    if (c < 1000) outp[b*1000 + c] = 0.5f * (e2[jj]*i2 + e3[jj]*i3);
  }
}

extern "C" void kernel_launch(void* const* d_in, const int* in_sizes, int n_in,
                              void* d_out, int out_size, void* d_ws, size_t ws_size,
                              hipStream_t stream)
{
  const float* attr_map = (const float*)d_in[0];
  const float* features = (const float*)d_in[1];
  const float* W1 = (const float*)d_in[2];
  const float* W2 = (const float*)d_in[3];
  const float* W3 = (const float*)d_in[4];
  float* outp = (float*)d_out;

  char* ws = (char*)d_ws;
  u16*   w1bp    = (u16*)ws;                       // 1,310,720 B
  float* W2T     = (float*)(ws + 1310720);         // 1,310,720 B
  float* partial = (float*)(ws + 2621440);         // 1,003,520 B
  float* l3p     = (float*)(ws + 3624960);         // 4,194,304 B (total 7.8 MB)

  kprep    <<<896, 256, 0, stream>>>(W1, W2, features, W3, w1bp, W2T, l3p);
  k1_main  <<<196, 512, 0, stream>>>(attr_map, w1bp, partial);
  k2c_final<<<64, 256, 0, stream>>>(partial, W2T, l3p, outp, outp + 64000);
}